// Round 9
// baseline (286.143 us; speedup 1.0000x reference)
//
#include <hip/hip_runtime.h>

#define E_TOTAL   800000
#define HID       128
#define EPB       256            // 4 waves x 64 edges (2 chains of 32) per block
#define LN_EPS    1e-5f
#define C2K       2.8853900817779268f   // 2*log2(e)

typedef __attribute__((ext_vector_type(8)))  short bs8;
typedef __attribute__((ext_vector_type(16))) float fx16;

__device__ __forceinline__ unsigned short f2bf(float f) {
    union { float f; unsigned int i; } c; c.f = f;
    unsigned int r = c.i + 0x7FFFu + ((c.i >> 16) & 1u);
    return (unsigned short)(r >> 16);
}
__device__ __forceinline__ unsigned int cvt_pk_bf16(float a, float b) {
    unsigned int r;
    asm("v_cvt_pk_bf16_f32 %0, %1, %2" : "=v"(r) : "v"(a), "v"(b));
    return r;
}
// a' = {a.lo32lanes, b.lo32lanes}, b' = {a.hi32lanes, b.hi32lanes}
__device__ __forceinline__ void pswap(unsigned int &a, unsigned int &b) {
    asm("v_permlane32_swap_b32 %0, %1" : "+v"(a), "+v"(b));
}
// sum of v over lane pair (l, l^32); the v_mov forces distinct regs (no self-swap).
__device__ __forceinline__ float psum32(float v) {
    union { float f; unsigned int u; } a, b;
    a.f = v;
    asm("v_mov_b32 %0, %1" : "=v"(b.u) : "v"(a.u));
    asm("v_permlane32_swap_b32 %0, %1" : "+v"(a.u), "+v"(b.u));
    return a.f + b.f;
}
// tanh of (arg / C2K) where caller pre-scaled arg by C2K: 4 instrs
__device__ __forceinline__ float tanh_pre(float arg) {
    float e = __builtin_amdgcn_exp2f(arg);
    float r = __builtin_amdgcn_rcpf(e + 1.0f);
    return fmaf(-2.0f, r, 1.0f);
}
__device__ __forceinline__ void ld16(const float* __restrict__ p, float* v) {
    #pragma unroll
    for (int q = 0; q < 4; ++q) {
        float4 t = reinterpret_cast<const float4*>(p)[q];
        v[q*4+0] = t.x; v[q*4+1] = t.y; v[q*4+2] = t.z; v[q*4+3] = t.w;
    }
}

// ---- prep: W fragments + constant tables (round-6 layout, no fold) ----
__global__ void prep(const float* __restrict__ Ws, const float* __restrict__ bs,
                     const float* __restrict__ gammas, const float* __restrict__ betas,
                     const float* __restrict__ w_out,
                     unsigned short* __restrict__ wf, float* __restrict__ T) {
    int t = blockIdx.x * blockDim.x + threadIdx.x;
    if (t < 6144) {
        int l  = t & 63;
        int fr = t >> 6;
        int ks = fr & 7;
        int rt = (fr >> 3) & 3;
        int L  = fr >> 5;
        int fo  = rt*32 + (l & 31);
        int fi0 = ks*16 + ((l >> 5) << 3);
        const float* src = Ws + L*HID*HID;
        unsigned short tmp[8];
        #pragma unroll
        for (int j = 0; j < 8; ++j) tmp[j] = f2bf(src[(fi0 + j)*HID + fo]);
        *reinterpret_cast<bs8*>(wf + t*8) = *reinterpret_cast<const bs8*>(tmp);
    } else if (t < 7424) {
        int u = t - 6144;
        int reg = u & 15, h = (u >> 4) & 1, rt = (u >> 5) & 3;
        int fout = rt*32 + (reg & 3) + 8*(reg >> 2) + 4*h;
        float v;
        if (u < 1152) {
            int L = u / 384;
            int c = (u / 128) % 3;
            const float* src = (c == 0) ? bs : ((c == 1) ? gammas : betas);
            v = src[L*HID + fout];
            if (c >= 1) v *= C2K;       // fold tanh's 2*log2(e) into gamma/beta
        } else {
            v = w_out[fout];
        }
        T[u] = v;
    }
}

// ---- prep: x -> bf16 ----
__global__ void xcast(const float* __restrict__ x, unsigned int* __restrict__ xb) {
    int t = blockIdx.x * blockDim.x + threadIdx.x;
    if (t >= 400000) return;
    const float4* p = reinterpret_cast<const float4*>(x) + (size_t)t*2;
    float4 a = p[0], b = p[1];
    uint4 o;
    o.x = cvt_pk_bf16(a.x, a.y);
    o.y = cvt_pk_bf16(a.z, a.w);
    o.z = cvt_pk_bf16(b.x, b.y);
    o.w = cvt_pk_bf16(b.z, b.w);
    reinterpret_cast<uint4*>(xb)[t] = o;
}

// ---- fused main kernel: 2 chains x 32 edges per wave, zero LDS/barriers ----
// ROUND 9 single change vs round 6: the layer loop is NOT unrolled
// (#pragma unroll 1). Fully-unrolled body was ~35-40 KB > 32 KB I$ ->
// front-end fetch-bound (constant ~270 us across structures, VALUBusy ~38%).
template<int XB>
__launch_bounds__(256, 1)
__global__ void edge_fused(const float* __restrict__ x,
                           const unsigned short* __restrict__ xb,
                           const int* __restrict__ eidx,
                           const unsigned short* __restrict__ wf,
                           const float* __restrict__ T,
                           const float* __restrict__ b_out,
                           float* __restrict__ out)
{
    const int t   = threadIdx.x;
    const int l   = t & 63;
    const int w   = t >> 6;
    const int l31 = l & 31;
    const int h   = l >> 5;
    const int hh  = h << 4;
    const int eA  = blockIdx.x * EPB + w*64 + l31;
    const int eB  = eA + 32;

    const int nsA = eidx[eA], ntA = eidx[E_TOTAL + eA];
    const int nsB = eidx[eB], ntB = eidx[E_TOTAL + eB];

    unsigned int wA[4][8], wB[4][8];
    if (XB) {
        #pragma unroll
        for (int rt = 0; rt < 4; ++rt) {
            const unsigned short* pA = xb + (rt < 2 ? nsA : ntA)*64 + (rt & 1)*32 + 4*h;
            const unsigned short* pB = xb + (rt < 2 ? nsB : ntB)*64 + (rt & 1)*32 + 4*h;
            #pragma unroll
            for (int g = 0; g < 4; ++g) {
                uint2 vA = *reinterpret_cast<const uint2*>(pA + g*8);
                uint2 vB = *reinterpret_cast<const uint2*>(pB + g*8);
                wA[rt][2*g] = vA.x; wA[rt][2*g+1] = vA.y;
                wB[rt][2*g] = vB.x; wB[rt][2*g+1] = vB.y;
            }
        }
    } else {
        #pragma unroll
        for (int rt = 0; rt < 4; ++rt) {
            const float* pA = x + (rt < 2 ? nsA : ntA)*64 + (rt & 1)*32 + 4*h;
            const float* pB = x + (rt < 2 ? nsB : ntB)*64 + (rt & 1)*32 + 4*h;
            #pragma unroll
            for (int g = 0; g < 4; ++g) {
                float4 vA = *reinterpret_cast<const float4*>(pA + g*8);
                float4 vB = *reinterpret_cast<const float4*>(pB + g*8);
                wA[rt][2*g]   = cvt_pk_bf16(vA.x, vA.y);
                wA[rt][2*g+1] = cvt_pk_bf16(vA.z, vA.w);
                wB[rt][2*g]   = cvt_pk_bf16(vB.x, vB.y);
                wB[rt][2*g+1] = cvt_pk_bf16(vB.z, vB.w);
            }
        }
    }

    float oA = 0.f, oB = 0.f;

    #pragma unroll 1
    for (int L = 0; L < 3; ++L) {
        const bs8* wbase = reinterpret_cast<const bs8*>(wf) + (L*32)*64 + l;
        const float* Tb = T + (L*3 + 0)*128 + hh;
        const float* Tg = T + (L*3 + 1)*128 + hh;
        const float* Te = T + (L*3 + 2)*128 + hh;

        // init acc with bias (folds +b into MFMA C)
        fx16 accA[4], accB[4];
        #pragma unroll
        for (int rt = 0; rt < 4; ++rt) {
            float bv[16]; ld16(Tb + rt*32, bv);
            #pragma unroll
            for (int j = 0; j < 16; ++j) { accA[rt][j] = bv[j]; accB[rt][j] = bv[j]; }
        }

        // Ct = W^T (A, global/L1, shared by both chains) @ H^T (B, in-register)
        #pragma unroll
        for (int ks = 0; ks < 8; ++ks) {
            const int r  = ks >> 1;
            const int mb = (ks & 1) * 4;
            pswap(wA[r][mb+0], wA[r][mb+2]);
            pswap(wA[r][mb+1], wA[r][mb+3]);
            pswap(wB[r][mb+0], wB[r][mb+2]);
            pswap(wB[r][mb+1], wB[r][mb+3]);
            unsigned int bwA[4] = { wA[r][mb+0], wA[r][mb+1], wA[r][mb+2], wA[r][mb+3] };
            unsigned int bwB[4] = { wB[r][mb+0], wB[r][mb+1], wB[r][mb+2], wB[r][mb+3] };
            bs8 bA = *reinterpret_cast<const bs8*>(bwA);
            bs8 bB = *reinterpret_cast<const bs8*>(bwB);
            #pragma unroll
            for (int rt = 0; rt < 4; ++rt) {
                bs8 a = wbase[(rt*8 + ks)*64];
                accA[rt] = __builtin_amdgcn_mfma_f32_32x32x16_bf16(a, bA, accA[rt], 0, 0, 0);
                accB[rt] = __builtin_amdgcn_mfma_f32_32x32x16_bf16(a, bB, accB[rt], 0, 0, 0);
            }
        }

        // LN stats: 4-way partial accumulators to shorten dependent chains
        float sA0=0.f,sA1=0.f,sA2=0.f,sA3=0.f, qA0=0.f,qA1=0.f,qA2=0.f,qA3=0.f;
        float sB0=0.f,sB1=0.f,sB2=0.f,sB3=0.f, qB0=0.f,qB1=0.f,qB2=0.f,qB3=0.f;
        #pragma unroll
        for (int rt = 0; rt < 4; ++rt) {
            #pragma unroll
            for (int j = 0; j < 16; j += 4) {
                float a0 = accA[rt][j],   b0 = accB[rt][j];
                float a1 = accA[rt][j+1], b1 = accB[rt][j+1];
                float a2 = accA[rt][j+2], b2 = accB[rt][j+2];
                float a3 = accA[rt][j+3], b3 = accB[rt][j+3];
                sA0 += a0; qA0 = fmaf(a0, a0, qA0);
                sA1 += a1; qA1 = fmaf(a1, a1, qA1);
                sA2 += a2; qA2 = fmaf(a2, a2, qA2);
                sA3 += a3; qA3 = fmaf(a3, a3, qA3);
                sB0 += b0; qB0 = fmaf(b0, b0, qB0);
                sB1 += b1; qB1 = fmaf(b1, b1, qB1);
                sB2 += b2; qB2 = fmaf(b2, b2, qB2);
                sB3 += b3; qB3 = fmaf(b3, b3, qB3);
            }
        }
        float sA = (sA0+sA1)+(sA2+sA3), qA = (qA0+qA1)+(qA2+qA3);
        float sB = (sB0+sB1)+(sB2+sB3), qB = (qB0+qB1)+(qB2+qB3);
        sA = psum32(sA); qA = psum32(qA);
        sB = psum32(sB); qB = psum32(qB);
        const float muA = sA * (1.f/128.f), muB = sB * (1.f/128.f);
        const float rrA = rsqrtf(qA*(1.f/128.f) - muA*muA + LN_EPS);
        const float rrB = rsqrtf(qB*(1.f/128.f) - muB*muB + LN_EPS);
        const float nmA = -muA * rrA, nmB = -muB * rrB;

        if (L < 2) {
            #pragma unroll
            for (int rt = 0; rt < 4; ++rt) {
                float gv[16], ev[16];        // pre-scaled by C2K
                ld16(Tg + rt*32, gv);
                ld16(Te + rt*32, ev);
                #pragma unroll
                for (int m = 0; m < 8; ++m) {
                    float aA0 = fmaf(fmaf(accA[rt][2*m],   rrA, nmA), gv[2*m],   ev[2*m]);
                    float aA1 = fmaf(fmaf(accA[rt][2*m+1], rrA, nmA), gv[2*m+1], ev[2*m+1]);
                    float aB0 = fmaf(fmaf(accB[rt][2*m],   rrB, nmB), gv[2*m],   ev[2*m]);
                    float aB1 = fmaf(fmaf(accB[rt][2*m+1], rrB, nmB), gv[2*m+1], ev[2*m+1]);
                    wA[rt][m] = cvt_pk_bf16(tanh_pre(aA0), tanh_pre(aA1));
                    wB[rt][m] = cvt_pk_bf16(tanh_pre(aB0), tanh_pre(aB1));
                }
            }
        } else {
            const float* Tw = T + 1152 + hh;   // unscaled
            #pragma unroll
            for (int rt = 0; rt < 4; ++rt) {
                float gv[16], ev[16], wv[16];
                ld16(Tg + rt*32, gv);
                ld16(Te + rt*32, ev);
                ld16(Tw + rt*32, wv);
                #pragma unroll
                for (int j = 0; j < 16; ++j) {
                    float aA = fmaf(fmaf(accA[rt][j], rrA, nmA), gv[j], ev[j]);
                    float aB = fmaf(fmaf(accB[rt][j], rrB, nmB), gv[j], ev[j]);
                    oA = fmaf(tanh_pre(aA), wv[j], oA);
                    oB = fmaf(tanh_pre(aB), wv[j], oB);
                }
            }
        }
    }

    oA = psum32(oA);
    oB = psum32(oB);
    if (l < 32) {
        const float bo = b_out[0];
        out[eA] = oA + bo;
        out[eB] = oB + bo;
    }
}

extern "C" void kernel_launch(void* const* d_in, const int* in_sizes, int n_in,
                              void* d_out, int out_size, void* d_ws, size_t ws_size,
                              hipStream_t stream) {
    const float* x      = (const float*)d_in[0];
    const int*   eidx   = (const int*)d_in[1];
    const float* Ws     = (const float*)d_in[2];
    const float* bs     = (const float*)d_in[3];
    const float* gammas = (const float*)d_in[4];
    const float* betas  = (const float*)d_in[5];
    const float* w_out  = (const float*)d_in[6];
    const float* b_out  = (const float*)d_in[7];
    float* out = (float*)d_out;

    unsigned short* wf = (unsigned short*)d_ws;                   // 98304 B
    float* T  = (float*)((char*)d_ws + 98304);                    // 5120 B -> ends 103424
    unsigned short* xb = (unsigned short*)((char*)d_ws + 103936); // 6.4 MB (aligned)

    const size_t need_xb = 103936 + 6400000ull;

    prep<<<29, 256, 0, stream>>>(Ws, bs, gammas, betas, w_out, wf, T);
    if (ws_size >= need_xb) {
        xcast<<<1563, 256, 0, stream>>>(x, (unsigned int*)xb);
        edge_fused<1><<<E_TOTAL/EPB, 256, 0, stream>>>(x, xb, eidx, wf, T, b_out, out);
    } else {
        edge_fused<0><<<E_TOTAL/EPB, 256, 0, stream>>>(x, xb, eidx, wf, T, b_out, out);
    }
}

// Round 10
// 171.149 us; speedup vs baseline: 1.6719x; 1.6719x over previous
//
#include <hip/hip_runtime.h>

#define E_TOTAL   800000
#define HID       128
#define EPB       128            // 4 waves x 32 edges per block
#define LN_EPS    1e-5f
#define C2K       2.8853900817779268f   // 2*log2(e)

typedef __attribute__((ext_vector_type(8)))  short bs8;
typedef __attribute__((ext_vector_type(16))) float fx16;

__device__ __forceinline__ unsigned short f2bf(float f) {
    union { float f; unsigned int i; } c; c.f = f;
    unsigned int r = c.i + 0x7FFFu + ((c.i >> 16) & 1u);
    return (unsigned short)(r >> 16);
}
__device__ __forceinline__ unsigned int cvt_pk_bf16(float a, float b) {
    unsigned int r;
    asm("v_cvt_pk_bf16_f32 %0, %1, %2" : "=v"(r) : "v"(a), "v"(b));
    return r;
}
// a' = {a.lo32lanes, b.lo32lanes}, b' = {a.hi32lanes, b.hi32lanes}
__device__ __forceinline__ void pswap(unsigned int &a, unsigned int &b) {
    asm("v_permlane32_swap_b32 %0, %1" : "+v"(a), "+v"(b));
}
// sum of v over lane pair (l, l^32); v_mov forces distinct regs (no self-swap).
__device__ __forceinline__ float psum32(float v) {
    union { float f; unsigned int u; } a, b;
    a.f = v;
    asm("v_mov_b32 %0, %1" : "=v"(b.u) : "v"(a.u));
    asm("v_permlane32_swap_b32 %0, %1" : "+v"(a.u), "+v"(b.u));
    return a.f + b.f;
}
// tanh of (arg / C2K) where caller pre-scaled arg by C2K
__device__ __forceinline__ float tanh_pre(float arg) {
    float e = __builtin_amdgcn_exp2f(arg);
    float r = __builtin_amdgcn_rcpf(e + 1.0f);
    return fmaf(-2.0f, r, 1.0f);
}
__device__ __forceinline__ void ld16s(const float* p, float* v) {
    #pragma unroll
    for (int q = 0; q < 4; ++q) {
        float4 t = reinterpret_cast<const float4*>(p)[q];
        v[q*4+0] = t.x; v[q*4+1] = t.y; v[q*4+2] = t.z; v[q*4+3] = t.w;
    }
}

// ---- prep: W fragments + constant tables (round-6 layout, no fold) ----
__global__ void prep(const float* __restrict__ Ws, const float* __restrict__ bs,
                     const float* __restrict__ gammas, const float* __restrict__ betas,
                     const float* __restrict__ w_out,
                     unsigned short* __restrict__ wf, float* __restrict__ T) {
    int t = blockIdx.x * blockDim.x + threadIdx.x;
    if (t < 6144) {
        int l  = t & 63;
        int fr = t >> 6;
        int ks = fr & 7;
        int rt = (fr >> 3) & 3;
        int L  = fr >> 5;
        int fo  = rt*32 + (l & 31);
        int fi0 = ks*16 + ((l >> 5) << 3);
        const float* src = Ws + L*HID*HID;
        unsigned short tmp[8];
        #pragma unroll
        for (int j = 0; j < 8; ++j) tmp[j] = f2bf(src[(fi0 + j)*HID + fo]);
        *reinterpret_cast<bs8*>(wf + t*8) = *reinterpret_cast<const bs8*>(tmp);
    } else if (t < 7424) {
        int u = t - 6144;
        int reg = u & 15, h = (u >> 4) & 1, rt = (u >> 5) & 3;
        int fout = rt*32 + (reg & 3) + 8*(reg >> 2) + 4*h;
        float v;
        if (u < 1152) {
            int L = u / 384;
            int c = (u / 128) % 3;
            const float* src = (c == 0) ? bs : ((c == 1) ? gammas : betas);
            v = src[L*HID + fout];
            if (c >= 1) v *= C2K;       // fold tanh's 2*log2(e) into gamma/beta
        } else {
            v = w_out[fout];
        }
        T[u] = v;
    }
}

// ---- prep: x -> bf16 ----
__global__ void xcast(const float* __restrict__ x, unsigned int* __restrict__ xb) {
    int t = blockIdx.x * blockDim.x + threadIdx.x;
    if (t >= 400000) return;
    const float4* p = reinterpret_cast<const float4*>(x) + (size_t)t*2;
    float4 a = p[0], b = p[1];
    uint4 o;
    o.x = cvt_pk_bf16(a.x, a.y);
    o.y = cvt_pk_bf16(a.z, a.w);
    o.z = cvt_pk_bf16(b.x, b.y);
    o.w = cvt_pk_bf16(b.z, b.w);
    reinterpret_cast<uint4*>(xb)[t] = o;
}

// ---- fused main kernel: 1 chain x 32 edges per wave ----
// ROUND 10: W fragments + tables staged in LDS via global_load_lds.
// Per-wave VMEM instrs drop ~250 -> ~45 (theory: per-CU TA path is the
// shared bottleneck pinning all prior rounds at ~270us / 38% VALUBusy).
template<int XB>
__launch_bounds__(256, 3)
__global__ void edge_fused(const float* __restrict__ x,
                           const unsigned short* __restrict__ xb,
                           const int* __restrict__ eidx,
                           const unsigned short* __restrict__ wf,
                           const float* __restrict__ T,
                           const float* __restrict__ b_out,
                           float* __restrict__ out)
{
    __shared__ __align__(16) unsigned short Wlds[16384];  // 32 KB, one layer, frag-linear
    __shared__ __align__(16) float Tlds[1296];            // 5184 B

    const int t   = threadIdx.x;
    const int l   = t & 63;
    const int w   = t >> 6;
    const int l31 = l & 31;
    const int h   = l >> 5;
    const int hh  = h << 4;
    const int e   = blockIdx.x * EPB + w*32 + l31;

    // ---- stage constant tables into LDS (wave w covers [w*1024, +1024) bytes) ----
    {
        const char* ts = (const char*)T;
        char* td = (char*)Tlds + w*1024;
        #pragma unroll
        for (int i = 0; i < 2; ++i) {
            int off = i*4096 + t*16;
            if (off < 5184) {
                __builtin_amdgcn_global_load_lds(
                    (const __attribute__((address_space(1))) unsigned int*)(ts + off),
                    (__attribute__((address_space(3))) unsigned int*)(td + i*4096), 16, 0, 0);
            }
        }
    }

    // ---- gather H into registers (1 chain) ----
    const int ns = eidx[e];
    const int nt = eidx[E_TOTAL + e];
    unsigned int wrd[4][8];
    if (XB) {
        #pragma unroll
        for (int rt = 0; rt < 4; ++rt) {
            const unsigned short* p = xb + (rt < 2 ? ns : nt)*64 + (rt & 1)*32 + 4*h;
            #pragma unroll
            for (int g = 0; g < 4; ++g) {
                uint2 v = *reinterpret_cast<const uint2*>(p + g*8);
                wrd[rt][2*g] = v.x; wrd[rt][2*g+1] = v.y;
            }
        }
    } else {
        #pragma unroll
        for (int rt = 0; rt < 4; ++rt) {
            const float* p = x + (rt < 2 ? ns : nt)*64 + (rt & 1)*32 + 4*h;
            #pragma unroll
            for (int g = 0; g < 4; ++g) {
                float4 v = *reinterpret_cast<const float4*>(p + g*8);
                wrd[rt][2*g]   = cvt_pk_bf16(v.x, v.y);
                wrd[rt][2*g+1] = cvt_pk_bf16(v.z, v.w);
            }
        }
    }

    float o0 = 0.f;

    #pragma unroll 1
    for (int L = 0; L < 3; ++L) {
        // ---- stage W[L] into LDS: wave w copies frags [w*8, w*8+8) (8 KB) ----
        {
            const char* wsrc = (const char*)wf + L*32768 + w*8192 + l*16;
            char* wdst = (char*)Wlds + w*8192;
            #pragma unroll
            for (int i = 0; i < 8; ++i) {
                __builtin_amdgcn_global_load_lds(
                    (const __attribute__((address_space(1))) unsigned int*)(wsrc + i*1024),
                    (__attribute__((address_space(3))) unsigned int*)(wdst + i*1024), 16, 0, 0);
            }
        }
        __syncthreads();   // staging complete (drains vmcnt); tables too on L=0

        const float* Tb = Tlds + (L*3 + 0)*128 + hh;
        const float* Tg = Tlds + (L*3 + 1)*128 + hh;
        const float* Te = Tlds + (L*3 + 2)*128 + hh;
        const bs8* wl = reinterpret_cast<const bs8*>(Wlds) + l;

        // init acc with bias
        fx16 acc[4];
        #pragma unroll
        for (int rt = 0; rt < 4; ++rt) {
            float bv[16]; ld16s(Tb + rt*32, bv);
            #pragma unroll
            for (int j = 0; j < 16; ++j) acc[rt][j] = bv[j];
        }

        // Ct = W^T (A, LDS) @ H^T (B, in-register via permlane)
        #pragma unroll
        for (int ks = 0; ks < 8; ++ks) {
            const int r  = ks >> 1;
            const int mb = (ks & 1) * 4;
            pswap(wrd[r][mb+0], wrd[r][mb+2]);
            pswap(wrd[r][mb+1], wrd[r][mb+3]);
            unsigned int bw[4] = { wrd[r][mb+0], wrd[r][mb+1], wrd[r][mb+2], wrd[r][mb+3] };
            bs8 b = *reinterpret_cast<const bs8*>(bw);
            #pragma unroll
            for (int rt = 0; rt < 4; ++rt) {
                bs8 a = wl[(rt*8 + ks)*64];
                acc[rt] = __builtin_amdgcn_mfma_f32_32x32x16_bf16(a, b, acc[rt], 0, 0, 0);
            }
        }

        // LN stats: 4-way partial accumulators
        float s0=0.f,s1=0.f,s2=0.f,s3=0.f, q0=0.f,q1=0.f,q2=0.f,q3=0.f;
        #pragma unroll
        for (int rt = 0; rt < 4; ++rt) {
            #pragma unroll
            for (int j = 0; j < 16; j += 4) {
                float a0 = acc[rt][j],   a1 = acc[rt][j+1];
                float a2 = acc[rt][j+2], a3 = acc[rt][j+3];
                s0 += a0; q0 = fmaf(a0, a0, q0);
                s1 += a1; q1 = fmaf(a1, a1, q1);
                s2 += a2; q2 = fmaf(a2, a2, q2);
                s3 += a3; q3 = fmaf(a3, a3, q3);
            }
        }
        float s = (s0+s1)+(s2+s3), q = (q0+q1)+(q2+q3);
        s = psum32(s); q = psum32(q);
        const float mu   = s * (1.f/128.f);
        const float rr   = rsqrtf(q*(1.f/128.f) - mu*mu + LN_EPS);
        const float nmur = -mu * rr;

        if (L < 2) {
            #pragma unroll
            for (int rt = 0; rt < 4; ++rt) {
                float gv[16], ev[16];        // pre-scaled by C2K
                ld16s(Tg + rt*32, gv);
                ld16s(Te + rt*32, ev);
                #pragma unroll
                for (int m = 0; m < 8; ++m) {
                    float a0 = fmaf(fmaf(acc[rt][2*m],   rr, nmur), gv[2*m],   ev[2*m]);
                    float a1 = fmaf(fmaf(acc[rt][2*m+1], rr, nmur), gv[2*m+1], ev[2*m+1]);
                    wrd[rt][m] = cvt_pk_bf16(tanh_pre(a0), tanh_pre(a1));
                }
            }
        } else {
            const float* Tw = Tlds + 1152 + hh;   // unscaled
            #pragma unroll
            for (int rt = 0; rt < 4; ++rt) {
                float gv[16], ev[16], wv[16];
                ld16s(Tg + rt*32, gv);
                ld16s(Te + rt*32, ev);
                ld16s(Tw + rt*32, wv);
                #pragma unroll
                for (int j = 0; j < 16; ++j) {
                    float a0 = fmaf(fmaf(acc[rt][j], rr, nmur), gv[j], ev[j]);
                    o0 = fmaf(tanh_pre(a0), wv[j], o0);
                }
            }
        }
        __syncthreads();   // all LDS reads done before next layer's stage overwrites
    }

    o0 = psum32(o0);
    if (l < 32) out[e] = o0 + b_out[0];
}

extern "C" void kernel_launch(void* const* d_in, const int* in_sizes, int n_in,
                              void* d_out, int out_size, void* d_ws, size_t ws_size,
                              hipStream_t stream) {
    const float* x      = (const float*)d_in[0];
    const int*   eidx   = (const int*)d_in[1];
    const float* Ws     = (const float*)d_in[2];
    const float* bs     = (const float*)d_in[3];
    const float* gammas = (const float*)d_in[4];
    const float* betas  = (const float*)d_in[5];
    const float* w_out  = (const float*)d_in[6];
    const float* b_out  = (const float*)d_in[7];
    float* out = (float*)d_out;

    unsigned short* wf = (unsigned short*)d_ws;                   // 98304 B
    float* T  = (float*)((char*)d_ws + 98304);                    // 5120 B used (+pad)
    unsigned short* xb = (unsigned short*)((char*)d_ws + 103936); // 6.4 MB (aligned)

    const size_t need_xb = 103936 + 6400000ull;

    prep<<<29, 256, 0, stream>>>(Ws, bs, gammas, betas, w_out, wf, T);
    if (ws_size >= need_xb) {
        xcast<<<1563, 256, 0, stream>>>(x, (unsigned int*)xb);
        edge_fused<1><<<E_TOTAL/EPB, 256, 0, stream>>>(x, xb, eidx, wf, T, b_out, out);
    } else {
        edge_fused<0><<<E_TOTAL/EPB, 256, 0, stream>>>(x, xb, eidx, wf, T, b_out, out);
    }
}

// Round 11
// 159.824 us; speedup vs baseline: 1.7904x; 1.0709x over previous
//
#include <hip/hip_runtime.h>

#define E_TOTAL   800000
#define HID       128
#define EPB       128            // 4 waves x 32 edges per block
#define LN_EPS    1e-5f
#define C2K       2.8853900817779268f   // 2*log2(e)

typedef __attribute__((ext_vector_type(8)))  short bs8;
typedef __attribute__((ext_vector_type(16))) float fx16;
typedef __attribute__((ext_vector_type(2)))  float f32x2;

__device__ __forceinline__ unsigned short f2bf(float f) {
    union { float f; unsigned int i; } c; c.f = f;
    unsigned int r = c.i + 0x7FFFu + ((c.i >> 16) & 1u);
    return (unsigned short)(r >> 16);
}
__device__ __forceinline__ unsigned int cvt_pk_bf16(float a, float b) {
    unsigned int r;
    asm("v_cvt_pk_bf16_f32 %0, %1, %2" : "=v"(r) : "v"(a), "v"(b));
    return r;
}
// a' = {a.lo32lanes, b.lo32lanes}, b' = {a.hi32lanes, b.hi32lanes}
__device__ __forceinline__ void pswap(unsigned int &a, unsigned int &b) {
    asm("v_permlane32_swap_b32 %0, %1" : "+v"(a), "+v"(b));
}
// sum of v over lane pair (l, l^32); v_mov forces distinct regs (no self-swap).
__device__ __forceinline__ float psum32(float v) {
    union { float f; unsigned int u; } a, b;
    a.f = v;
    asm("v_mov_b32 %0, %1" : "=v"(b.u) : "v"(a.u));
    asm("v_permlane32_swap_b32 %0, %1" : "+v"(a.u), "+v"(b.u));
    return a.f + b.f;
}
// tanh of (arg / C2K) where caller pre-scaled arg by C2K
__device__ __forceinline__ float tanh_pre(float arg) {
    float e = __builtin_amdgcn_exp2f(arg);
    float r = __builtin_amdgcn_rcpf(e + 1.0f);
    return fmaf(-2.0f, r, 1.0f);
}
__device__ __forceinline__ f32x2 fma2(f32x2 a, f32x2 b, f32x2 c) {
    return __builtin_elementwise_fma(a, b, c);   // -> v_pk_fma_f32
}
__device__ __forceinline__ void ld16s(const float* p, float* v) {
    #pragma unroll
    for (int q = 0; q < 4; ++q) {
        float4 t = reinterpret_cast<const float4*>(p)[q];
        v[q*4+0] = t.x; v[q*4+1] = t.y; v[q*4+2] = t.z; v[q*4+3] = t.w;
    }
}

// ---- prep: W fragments + constant tables (round-6 layout, no fold) ----
__global__ void prep(const float* __restrict__ Ws, const float* __restrict__ bs,
                     const float* __restrict__ gammas, const float* __restrict__ betas,
                     const float* __restrict__ w_out,
                     unsigned short* __restrict__ wf, float* __restrict__ T) {
    int t = blockIdx.x * blockDim.x + threadIdx.x;
    if (t < 6144) {
        int l  = t & 63;
        int fr = t >> 6;
        int ks = fr & 7;
        int rt = (fr >> 3) & 3;
        int L  = fr >> 5;
        int fo  = rt*32 + (l & 31);
        int fi0 = ks*16 + ((l >> 5) << 3);
        const float* src = Ws + L*HID*HID;
        unsigned short tmp[8];
        #pragma unroll
        for (int j = 0; j < 8; ++j) tmp[j] = f2bf(src[(fi0 + j)*HID + fo]);
        *reinterpret_cast<bs8*>(wf + t*8) = *reinterpret_cast<const bs8*>(tmp);
    } else if (t < 7424) {
        int u = t - 6144;
        int reg = u & 15, h = (u >> 4) & 1, rt = (u >> 5) & 3;
        int fout = rt*32 + (reg & 3) + 8*(reg >> 2) + 4*h;
        float v;
        if (u < 1152) {
            int L = u / 384;
            int c = (u / 128) % 3;
            const float* src = (c == 0) ? bs : ((c == 1) ? gammas : betas);
            v = src[L*HID + fout];
            if (c >= 1) v *= C2K;       // fold tanh's 2*log2(e) into gamma/beta
        } else {
            v = w_out[fout];
        }
        T[u] = v;
    }
}

// ---- prep: x -> bf16 ----
__global__ void xcast(const float* __restrict__ x, unsigned int* __restrict__ xb) {
    int t = blockIdx.x * blockDim.x + threadIdx.x;
    if (t >= 400000) return;
    const float4* p = reinterpret_cast<const float4*>(x) + (size_t)t*2;
    float4 a = p[0], b = p[1];
    uint4 o;
    o.x = cvt_pk_bf16(a.x, a.y);
    o.y = cvt_pk_bf16(a.z, a.w);
    o.z = cvt_pk_bf16(b.x, b.y);
    o.w = cvt_pk_bf16(b.z, b.w);
    reinterpret_cast<uint4*>(xb)[t] = o;
}

// ---- fused main kernel: 1 chain x 32 edges per wave, W+tables in LDS ----
// ROUND 11 single change vs round 10: stats / LN-apply / output-dot use
// by-value f32x2 packed math (v_pk_fma_f32, 2 f32 per lane-instr).
template<int XB>
__launch_bounds__(256, 3)
__global__ void edge_fused(const float* __restrict__ x,
                           const unsigned short* __restrict__ xb,
                           const int* __restrict__ eidx,
                           const unsigned short* __restrict__ wf,
                           const float* __restrict__ T,
                           const float* __restrict__ b_out,
                           float* __restrict__ out)
{
    __shared__ __align__(16) unsigned short Wlds[16384];  // 32 KB, one layer, frag-linear
    __shared__ __align__(16) float Tlds[1296];            // 5184 B

    const int t   = threadIdx.x;
    const int l   = t & 63;
    const int w   = t >> 6;
    const int l31 = l & 31;
    const int h   = l >> 5;
    const int hh  = h << 4;
    const int e   = blockIdx.x * EPB + w*32 + l31;

    // ---- stage constant tables into LDS ----
    {
        const char* ts = (const char*)T;
        char* td = (char*)Tlds + w*1024;
        #pragma unroll
        for (int i = 0; i < 2; ++i) {
            int off = i*4096 + t*16;
            if (off < 5184) {
                __builtin_amdgcn_global_load_lds(
                    (const __attribute__((address_space(1))) unsigned int*)(ts + off),
                    (__attribute__((address_space(3))) unsigned int*)(td + i*4096), 16, 0, 0);
            }
        }
    }

    // ---- gather H into registers (1 chain) ----
    const int ns = eidx[e];
    const int nt = eidx[E_TOTAL + e];
    unsigned int wrd[4][8];
    if (XB) {
        #pragma unroll
        for (int rt = 0; rt < 4; ++rt) {
            const unsigned short* p = xb + (rt < 2 ? ns : nt)*64 + (rt & 1)*32 + 4*h;
            #pragma unroll
            for (int g = 0; g < 4; ++g) {
                uint2 v = *reinterpret_cast<const uint2*>(p + g*8);
                wrd[rt][2*g] = v.x; wrd[rt][2*g+1] = v.y;
            }
        }
    } else {
        #pragma unroll
        for (int rt = 0; rt < 4; ++rt) {
            const float* p = x + (rt < 2 ? ns : nt)*64 + (rt & 1)*32 + 4*h;
            #pragma unroll
            for (int g = 0; g < 4; ++g) {
                float4 v = *reinterpret_cast<const float4*>(p + g*8);
                wrd[rt][2*g]   = cvt_pk_bf16(v.x, v.y);
                wrd[rt][2*g+1] = cvt_pk_bf16(v.z, v.w);
            }
        }
    }

    f32x2 oacc0 = {0.f, 0.f}, oacc1 = {0.f, 0.f};

    #pragma unroll 1
    for (int L = 0; L < 3; ++L) {
        // ---- stage W[L] into LDS: wave w copies frags [w*8, w*8+8) (8 KB) ----
        {
            const char* wsrc = (const char*)wf + L*32768 + w*8192 + l*16;
            char* wdst = (char*)Wlds + w*8192;
            #pragma unroll
            for (int i = 0; i < 8; ++i) {
                __builtin_amdgcn_global_load_lds(
                    (const __attribute__((address_space(1))) unsigned int*)(wsrc + i*1024),
                    (__attribute__((address_space(3))) unsigned int*)(wdst + i*1024), 16, 0, 0);
            }
        }
        __syncthreads();   // staging complete (drains vmcnt); tables too on L=0

        const float* Tb = Tlds + (L*3 + 0)*128 + hh;
        const float* Tg = Tlds + (L*3 + 1)*128 + hh;
        const float* Te = Tlds + (L*3 + 2)*128 + hh;
        const bs8* wl = reinterpret_cast<const bs8*>(Wlds) + l;

        // init acc with bias
        fx16 acc[4];
        #pragma unroll
        for (int rt = 0; rt < 4; ++rt) {
            float bv[16]; ld16s(Tb + rt*32, bv);
            #pragma unroll
            for (int j = 0; j < 16; ++j) acc[rt][j] = bv[j];
        }

        // Ct = W^T (A, LDS) @ H^T (B, in-register via permlane)
        #pragma unroll
        for (int ks = 0; ks < 8; ++ks) {
            const int r  = ks >> 1;
            const int mb = (ks & 1) * 4;
            pswap(wrd[r][mb+0], wrd[r][mb+2]);
            pswap(wrd[r][mb+1], wrd[r][mb+3]);
            unsigned int bw[4] = { wrd[r][mb+0], wrd[r][mb+1], wrd[r][mb+2], wrd[r][mb+3] };
            bs8 b = *reinterpret_cast<const bs8*>(bw);
            #pragma unroll
            for (int rt = 0; rt < 4; ++rt) {
                bs8 a = wl[(rt*8 + ks)*64];
                acc[rt] = __builtin_amdgcn_mfma_f32_32x32x16_bf16(a, b, acc[rt], 0, 0, 0);
            }
        }

        // LN stats: packed f32x2 partials (v_pk_add/v_pk_fma)
        f32x2 s0 = {0,0}, s1 = {0,0}, q0 = {0,0}, q1 = {0,0};
        #pragma unroll
        for (int rt = 0; rt < 4; ++rt) {
            #pragma unroll
            for (int j = 0; j < 16; j += 4) {
                f32x2 p0 = { acc[rt][j],   acc[rt][j+1] };
                f32x2 p1 = { acc[rt][j+2], acc[rt][j+3] };
                s0 += p0; q0 = fma2(p0, p0, q0);
                s1 += p1; q1 = fma2(p1, p1, q1);
            }
        }
        float s = (s0.x + s0.y) + (s1.x + s1.y);
        float q = (q0.x + q0.y) + (q1.x + q1.y);
        s = psum32(s); q = psum32(q);
        const float mu   = s * (1.f/128.f);
        const float rr   = rsqrtf(q*(1.f/128.f) - mu*mu + LN_EPS);
        const float nmur = -mu * rr;
        const f32x2 rr2  = { rr, rr };
        const f32x2 nm2  = { nmur, nmur };

        if (L < 2) {
            #pragma unroll
            for (int rt = 0; rt < 4; ++rt) {
                float gv[16], ev[16];        // pre-scaled by C2K
                ld16s(Tg + rt*32, gv);
                ld16s(Te + rt*32, ev);
                #pragma unroll
                for (int m = 0; m < 8; ++m) {
                    f32x2 p  = { acc[rt][2*m], acc[rt][2*m+1] };
                    f32x2 g2 = { gv[2*m], gv[2*m+1] };
                    f32x2 e2 = { ev[2*m], ev[2*m+1] };
                    f32x2 arg = fma2(fma2(p, rr2, nm2), g2, e2);
                    wrd[rt][m] = cvt_pk_bf16(tanh_pre(arg.x), tanh_pre(arg.y));
                }
            }
        } else {
            const float* Tw = Tlds + 1152 + hh;   // unscaled
            #pragma unroll
            for (int rt = 0; rt < 4; ++rt) {
                float gv[16], ev[16], wv[16];
                ld16s(Tg + rt*32, gv);
                ld16s(Te + rt*32, ev);
                ld16s(Tw + rt*32, wv);
                #pragma unroll
                for (int m = 0; m < 8; ++m) {
                    f32x2 p  = { acc[rt][2*m], acc[rt][2*m+1] };
                    f32x2 g2 = { gv[2*m], gv[2*m+1] };
                    f32x2 e2 = { ev[2*m], ev[2*m+1] };
                    f32x2 arg = fma2(fma2(p, rr2, nm2), g2, e2);
                    f32x2 u2 = { tanh_pre(arg.x), tanh_pre(arg.y) };
                    f32x2 w2 = { wv[2*m], wv[2*m+1] };
                    if (m & 1) oacc1 = fma2(u2, w2, oacc1);
                    else       oacc0 = fma2(u2, w2, oacc0);
                }
            }
        }
        __syncthreads();   // all LDS reads done before next layer's stage overwrites
    }

    float o0 = (oacc0.x + oacc0.y) + (oacc1.x + oacc1.y);
    o0 = psum32(o0);
    if (l < 32) out[e] = o0 + b_out[0];
}

extern "C" void kernel_launch(void* const* d_in, const int* in_sizes, int n_in,
                              void* d_out, int out_size, void* d_ws, size_t ws_size,
                              hipStream_t stream) {
    const float* x      = (const float*)d_in[0];
    const int*   eidx   = (const int*)d_in[1];
    const float* Ws     = (const float*)d_in[2];
    const float* bs     = (const float*)d_in[3];
    const float* gammas = (const float*)d_in[4];
    const float* betas  = (const float*)d_in[5];
    const float* w_out  = (const float*)d_in[6];
    const float* b_out  = (const float*)d_in[7];
    float* out = (float*)d_out;

    unsigned short* wf = (unsigned short*)d_ws;                   // 98304 B
    float* T  = (float*)((char*)d_ws + 98304);                    // 5120 B used (+pad)
    unsigned short* xb = (unsigned short*)((char*)d_ws + 103936); // 6.4 MB (aligned)

    const size_t need_xb = 103936 + 6400000ull;

    prep<<<29, 256, 0, stream>>>(Ws, bs, gammas, betas, w_out, wf, T);
    if (ws_size >= need_xb) {
        xcast<<<1563, 256, 0, stream>>>(x, (unsigned int*)xb);
        edge_fused<1><<<E_TOTAL/EPB, 256, 0, stream>>>(x, xb, eidx, wf, T, b_out, out);
    } else {
        edge_fused<0><<<E_TOTAL/EPB, 256, 0, stream>>>(x, xb, eidx, wf, T, b_out, out);
    }
}